// Round 1
// baseline (64.498 us; speedup 1.0000x reference)
//
#include <hip/hip_runtime.h>
#include <math.h>

// Problem sizes
constexpr int H = 1024;
constexpr int V = 50257;
constexpr int L = 64;

// Workspace layout (float offsets)
constexpr int OFF_ALOG = 0;            // 64 attention logits
constexpr int OFF_XCAT = 64;           // 2048: [embedded | attn_applied]
constexpr int OFF_X    = 2112;         // 1024: relu(comb)
constexpr int OFF_G    = 3136;         // 6144: gi (3072) | gh (3072)
constexpr int OFF_LOG  = 9280;         // V: output logits
constexpr int NBLK6    = (V + 15) / 16; // 3142 blocks in out-proj
constexpr int OFF_PAIR = OFF_LOG + V;  // 2*NBLK6 (max, sumexp) pairs
constexpr int OFF_MS   = OFF_PAIR + 2 * NBLK6; // {M, log S}

// ---------------- K1: attention logits: one block per logit ----------------
__global__ void k1_attn_logits(const int* __restrict__ idx_p,
                               const float* __restrict__ hid,
                               const float* __restrict__ emb,
                               const float* __restrict__ attn_W,
                               const float* __restrict__ attn_b,
                               float* __restrict__ ws) {
    const int l = blockIdx.x;            // 0..63
    const int tid = threadIdx.x;         // 256
    const int idx = idx_p[0];
    const float* wrow = attn_W + (size_t)l * (2 * H);
    const float* erow = emb + (size_t)idx * H;
    float acc = 0.f;
    for (int k = tid; k < 2 * H; k += 256) {
        float c = (k < H) ? erow[k] : hid[k - H];
        acc += wrow[k] * c;
    }
    for (int off = 32; off > 0; off >>= 1) acc += __shfl_down(acc, off);
    __shared__ float sred[4];
    const int lane = tid & 63, wid = tid >> 6;
    if (lane == 0) sred[wid] = acc;
    __syncthreads();
    if (tid == 0)
        ws[OFF_ALOG + l] = sred[0] + sred[1] + sred[2] + sred[3] + attn_b[l];
}

// -------- K2: softmax (redundant per block) + attn_applied + xcat ----------
__global__ void k2_attn_apply(const int* __restrict__ idx_p,
                              const float* __restrict__ emb,
                              const float* __restrict__ enc,
                              float* __restrict__ ws,
                              float* __restrict__ out) {
    __shared__ float slog[L];
    __shared__ float wls[L];
    const int tid = threadIdx.x;          // 256
    const int col = blockIdx.x * 256 + tid; // 4 blocks -> 1024 cols
    if (tid < L) slog[tid] = ws[OFF_ALOG + tid];
    __syncthreads();
    if (tid < L) {
        float m = -INFINITY;
        for (int i = 0; i < L; ++i) m = fmaxf(m, slog[i]);
        float s = 0.f;
        for (int i = 0; i < L; ++i) s += expf(slog[i] - m);
        wls[tid] = expf(slog[tid] - m) / s;
    }
    __syncthreads();
    if (blockIdx.x == 0 && tid < L) out[V + H + tid] = wls[tid];
    float acc = 0.f;
    for (int l = 0; l < L; ++l) acc += wls[l] * enc[l * H + col];
    const int idx = idx_p[0];
    ws[OFF_XCAT + col] = emb[(size_t)idx * H + col];
    ws[OFF_XCAT + H + col] = acc;
}

// ---------------- K3: x = relu(comb_W @ xcat + comb_b), wave/row -----------
__global__ void k3_comb(const float* __restrict__ comb_W,
                        const float* __restrict__ comb_b,
                        float* __restrict__ ws) {
    __shared__ float4 sx[512]; // 2048 floats
    const int tid = threadIdx.x; // 256
    const float4* xc4 = reinterpret_cast<const float4*>(ws + OFF_XCAT);
    sx[tid] = xc4[tid];
    sx[tid + 256] = xc4[tid + 256];
    __syncthreads();
    const int lane = tid & 63, wid = tid >> 6;
    const int row = blockIdx.x * 4 + wid; // 256 blocks * 4 waves = 1024 rows
    const float4* w4 = reinterpret_cast<const float4*>(comb_W + (size_t)row * (2 * H));
    float acc = 0.f;
#pragma unroll
    for (int it = 0; it < 8; ++it) {
        float4 a = w4[lane + it * 64];
        float4 b = sx[lane + it * 64];
        acc += a.x * b.x + a.y * b.y + a.z * b.z + a.w * b.w;
    }
    for (int off = 32; off > 0; off >>= 1) acc += __shfl_down(acc, off);
    if (lane == 0) ws[OFF_X + row] = fmaxf(acc + comb_b[row], 0.f);
}

// ---------------- K4: gi/gh GEMV, wave/row over 6144 rows ------------------
__global__ void k4_gru_gemv(const float* __restrict__ w_ih,
                            const float* __restrict__ w_hh,
                            const float* __restrict__ b_ih,
                            const float* __restrict__ b_hh,
                            const float* __restrict__ hid,
                            float* __restrict__ ws) {
    __shared__ float4 sv[256]; // 1024 floats
    const int tid = threadIdx.x; // 256
    const int row0 = blockIdx.x * 4; // 1536 blocks
    const bool is_h = (row0 >= 3 * H);
    const float* vec = is_h ? hid : (ws + OFF_X);
    sv[tid] = reinterpret_cast<const float4*>(vec)[tid];
    __syncthreads();
    const int lane = tid & 63, wid = tid >> 6;
    const int row = row0 + wid;
    const int lrow = is_h ? row - 3 * H : row;
    const float* W = is_h ? w_hh : w_ih;
    const float* B = is_h ? b_hh : b_ih;
    const float4* w4 = reinterpret_cast<const float4*>(W + (size_t)lrow * H);
    float acc = 0.f;
#pragma unroll
    for (int it = 0; it < 4; ++it) {
        float4 a = w4[lane + it * 64];
        float4 b = sv[lane + it * 64];
        acc += a.x * b.x + a.y * b.y + a.z * b.z + a.w * b.w;
    }
    for (int off = 32; off > 0; off >>= 1) acc += __shfl_down(acc, off);
    if (lane == 0) ws[OFF_G + row] = acc + B[lrow];
}

// ---------------- K5: GRU gates -> h_new -> d_out[V .. V+H) ----------------
__global__ void k5_gates(const float* __restrict__ hid,
                         const float* __restrict__ ws,
                         float* __restrict__ out) {
    const int t = blockIdx.x * 256 + threadIdx.x; // 4 blocks
    const float* g = ws + OFF_G;
    const float ir = g[t], iz = g[H + t], in_ = g[2 * H + t];
    const float hr = g[3 * H + t], hz = g[4 * H + t], hn = g[5 * H + t];
    const float r = 1.f / (1.f + expf(-(ir + hr)));
    const float z = 1.f / (1.f + expf(-(iz + hz)));
    const float n = tanhf(in_ + r * hn);
    out[V + t] = (1.f - z) * n + z * hid[t];
}

// ------- K6: big out-proj GEMV (wave/row, 16 rows/block) + partials --------
__global__ __launch_bounds__(1024) void k6_outproj(
        const float* __restrict__ out_W,
        const float* __restrict__ out_b,
        const float* __restrict__ hnew, // = d_out + V
        float* __restrict__ ws) {
    __shared__ float4 sh[256]; // h_new, 1024 floats
    __shared__ float srow[16];
    const int tid = threadIdx.x; // 1024
    if (tid < 256) sh[tid] = reinterpret_cast<const float4*>(hnew)[tid];
    __syncthreads();
    const int lane = tid & 63, wid = tid >> 6;
    const int row = blockIdx.x * 16 + wid;
    float logit = -INFINITY;
    if (row < V) {
        const float4* w4 = reinterpret_cast<const float4*>(out_W + (size_t)row * H);
        float acc = 0.f;
#pragma unroll
        for (int it = 0; it < 4; ++it) {
            float4 a = w4[lane + it * 64];
            float4 b = sh[lane + it * 64];
            acc += a.x * b.x + a.y * b.y + a.z * b.z + a.w * b.w;
        }
        for (int off = 32; off > 0; off >>= 1) acc += __shfl_down(acc, off);
        if (lane == 0) {
            logit = acc + out_b[row];
            ws[OFF_LOG + row] = logit;
        }
    }
    if (lane == 0) srow[wid] = logit;
    __syncthreads();
    if (tid == 0) {
        float m = -INFINITY;
        for (int i = 0; i < 16; ++i) m = fmaxf(m, srow[i]);
        float s = 0.f;
        for (int i = 0; i < 16; ++i)
            if (srow[i] > -INFINITY) s += expf(srow[i] - m);
        ws[OFF_PAIR + 2 * blockIdx.x] = m;
        ws[OFF_PAIR + 2 * blockIdx.x + 1] = s;
    }
}

// ---------------- K7: combine (m,s) pairs -> global (M, log S) -------------
__global__ void k7_lse_combine(float* __restrict__ ws) {
    const int tid = threadIdx.x; // 256
    float m = -INFINITY, s = 0.f;
    for (int i = tid; i < NBLK6; i += 256) {
        const float mi = ws[OFF_PAIR + 2 * i];
        const float si = ws[OFF_PAIR + 2 * i + 1];
        const float M = fmaxf(m, mi);
        s = s * expf(m - M) + si * expf(mi - M);
        m = M;
    }
    for (int off = 32; off > 0; off >>= 1) {
        const float mo = __shfl_down(m, off);
        const float so = __shfl_down(s, off);
        const float M = fmaxf(m, mo);
        s = s * expf(m - M) + so * expf(mo - M);
        m = M;
    }
    __shared__ float sm[4], ss[4];
    const int lane = tid & 63, wid = tid >> 6;
    if (lane == 0) { sm[wid] = m; ss[wid] = s; }
    __syncthreads();
    if (tid == 0) {
        float M = sm[0], S = ss[0];
        for (int i = 1; i < 4; ++i) {
            const float Mn = fmaxf(M, sm[i]);
            S = S * expf(M - Mn) + ss[i] * expf(sm[i] - Mn);
            M = Mn;
        }
        ws[OFF_MS] = M;
        ws[OFF_MS + 1] = logf(S);
    }
}

// ---------------- K8: write log-softmax to d_out[0..V) ---------------------
__global__ void k8_logsoftmax(const float* __restrict__ ws,
                              float* __restrict__ out) {
    const int i = blockIdx.x * 256 + threadIdx.x;
    if (i < V) out[i] = ws[OFF_LOG + i] - ws[OFF_MS] - ws[OFF_MS + 1];
}

extern "C" void kernel_launch(void* const* d_in, const int* in_sizes, int n_in,
                              void* d_out, int out_size, void* d_ws, size_t ws_size,
                              hipStream_t stream) {
    const int*   idx    = (const int*)d_in[0];
    const float* hid    = (const float*)d_in[1];
    const float* enc    = (const float*)d_in[2];
    const float* emb    = (const float*)d_in[3];
    const float* attn_W = (const float*)d_in[4];
    const float* attn_b = (const float*)d_in[5];
    const float* comb_W = (const float*)d_in[6];
    const float* comb_b = (const float*)d_in[7];
    const float* w_ih   = (const float*)d_in[8];
    const float* w_hh   = (const float*)d_in[9];
    const float* b_ih   = (const float*)d_in[10];
    const float* b_hh   = (const float*)d_in[11];
    const float* out_W  = (const float*)d_in[12];
    const float* out_b  = (const float*)d_in[13];
    float* out = (float*)d_out;
    float* ws  = (float*)d_ws;

    k1_attn_logits<<<L, 256, 0, stream>>>(idx, hid, emb, attn_W, attn_b, ws);
    k2_attn_apply<<<H / 256, 256, 0, stream>>>(idx, emb, enc, ws, out);
    k3_comb<<<H / 4, 256, 0, stream>>>(comb_W, comb_b, ws);
    k4_gru_gemv<<<(6 * H) / 4, 256, 0, stream>>>(w_ih, w_hh, b_ih, b_hh, hid, ws);
    k5_gates<<<H / 256, 256, 0, stream>>>(hid, ws, out);
    k6_outproj<<<NBLK6, 1024, 0, stream>>>(out_W, out_b, out + V, ws);
    k7_lse_combine<<<1, 256, 0, stream>>>(ws);
    k8_logsoftmax<<<(V + 255) / 256, 256, 0, stream>>>(ws, out);
}

// Round 2
// 62.653 us; speedup vs baseline: 1.0294x; 1.0294x over previous
//
#include <hip/hip_runtime.h>
#include <math.h>

// Problem sizes
constexpr int H = 1024;
constexpr int V = 50257;
constexpr int L = 64;

// Workspace layout (float offsets)
constexpr int OFF_ALOG = 0;              // 64 attention logits
constexpr int OFF_GH   = 64;             // 3072: gh = w_hh@h0 + b_hh
constexpr int OFF_X    = 64 + 3 * H;     // 1024: x = relu(comb)
constexpr int OFF_LOG  = OFF_X + H;      // V: output logits
constexpr int NBLKD    = (V + 15) / 16;  // 3142 blocks in out-proj
constexpr int OFF_PAIR = OFF_LOG + V;    // 2*NBLKD (max, sumexp) pairs

__device__ __forceinline__ float wave_reduce(float acc) {
    for (int off = 32; off > 0; off >>= 1) acc += __shfl_down(acc, off);
    return acc;
}

__device__ __forceinline__ float dot4(float4 a, float4 b) {
    return a.x * b.x + a.y * b.y + a.z * b.z + a.w * b.w;
}

// ---- A: attention logits (blocks 0..63) || gh GEMV (blocks 64..831) -------
__global__ __launch_bounds__(256) void kA(const int* __restrict__ idx_p,
                                          const float* __restrict__ hid,
                                          const float* __restrict__ emb,
                                          const float* __restrict__ attn_W,
                                          const float* __restrict__ attn_b,
                                          const float* __restrict__ w_hh,
                                          const float* __restrict__ b_hh,
                                          float* __restrict__ ws) {
    const int tid = threadIdx.x;
    const int lane = tid & 63, wid = tid >> 6;
    if (blockIdx.x < 64) {
        const int l = blockIdx.x;
        const int idx = idx_p[0];
        const float4* w4 = reinterpret_cast<const float4*>(attn_W + (size_t)l * (2 * H));
        const float4* e4 = reinterpret_cast<const float4*>(emb + (size_t)idx * H);
        const float4* h4 = reinterpret_cast<const float4*>(hid);
        float acc = dot4(w4[tid], e4[tid]) + dot4(w4[tid + 256], h4[tid]);
        acc = wave_reduce(acc);
        __shared__ float sred[4];
        if (lane == 0) sred[wid] = acc;
        __syncthreads();
        if (tid == 0)
            ws[OFF_ALOG + l] = sred[0] + sred[1] + sred[2] + sred[3] + attn_b[l];
    } else {
        __shared__ float4 sv[256];
        sv[tid] = reinterpret_cast<const float4*>(hid)[tid];
        __syncthreads();
        const int row = (blockIdx.x - 64) * 4 + wid;  // 0..3071
        const float4* w4 = reinterpret_cast<const float4*>(w_hh + (size_t)row * H);
        float acc = 0.f;
#pragma unroll
        for (int it = 0; it < 4; ++it)
            acc += dot4(w4[lane + it * 64], sv[lane + it * 64]);
        acc = wave_reduce(acc);
        if (lane == 0) ws[OFF_GH + row] = acc + b_hh[row];
    }
}

// ---- B: softmax + attn_applied + xcat + comb GEMV (256 blocks) ------------
__global__ __launch_bounds__(256) void kB(const int* __restrict__ idx_p,
                                          const float* __restrict__ emb,
                                          const float* __restrict__ enc,
                                          const float* __restrict__ comb_W,
                                          const float* __restrict__ comb_b,
                                          float* __restrict__ ws,
                                          float* __restrict__ out) {
    __shared__ float slog[L];
    __shared__ float wls[L];
    __shared__ float4 sx[512];  // xcat: [embedded | attn_applied], 2048 floats
    const int tid = threadIdx.x;
    if (tid < L) slog[tid] = ws[OFF_ALOG + tid];
    __syncthreads();
    if (tid < L) {
        float m = -INFINITY;
        for (int i = 0; i < L; ++i) m = fmaxf(m, slog[i]);
        float s = 0.f;
        for (int i = 0; i < L; ++i) s += expf(slog[i] - m);
        wls[tid] = expf(slog[tid] - m) / s;
        if (blockIdx.x == 0) out[V + H + tid] = wls[tid];
    }
    __syncthreads();
    const int idx = idx_p[0];
    sx[tid] = reinterpret_cast<const float4*>(emb + (size_t)idx * H)[tid];
    {
        const float4* e4 = reinterpret_cast<const float4*>(enc);
        float4 acc4 = {0.f, 0.f, 0.f, 0.f};
#pragma unroll 8
        for (int l = 0; l < L; ++l) {
            const float w = wls[l];
            const float4 v = e4[l * 256 + tid];
            acc4.x += w * v.x; acc4.y += w * v.y;
            acc4.z += w * v.z; acc4.w += w * v.w;
        }
        sx[256 + tid] = acc4;
    }
    __syncthreads();
    const int lane = tid & 63, wid = tid >> 6;
    const int row = blockIdx.x * 4 + wid;  // 0..1023
    const float4* w4 = reinterpret_cast<const float4*>(comb_W + (size_t)row * (2 * H));
    float acc = 0.f;
#pragma unroll
    for (int it = 0; it < 8; ++it)
        acc += dot4(w4[lane + it * 64], sx[lane + it * 64]);
    acc = wave_reduce(acc);
    if (lane == 0) ws[OFF_X + row] = fmaxf(acc + comb_b[row], 0.f);
}

// ---- C: gi GEMV + GRU gates fused (256 blocks x 768 threads) --------------
// Block b owns t in [4b, 4b+4); computes the 12 w_ih rows {g*H + t} it needs.
__global__ __launch_bounds__(768) void kC(const float* __restrict__ w_ih,
                                          const float* __restrict__ b_ih,
                                          const float* __restrict__ hid,
                                          float* __restrict__ ws,
                                          float* __restrict__ out) {
    __shared__ float4 sx4[256];  // x, 1024 floats
    __shared__ float gi_s[12];
    const int tid = threadIdx.x;
    if (tid < 256) sx4[tid] = reinterpret_cast<const float4*>(ws + OFF_X)[tid];
    __syncthreads();
    const int lane = tid & 63, wid = tid >> 6;  // wid 0..11
    const int g = wid >> 2, i = wid & 3;
    const int row = g * H + blockIdx.x * 4 + i;
    const float4* w4 = reinterpret_cast<const float4*>(w_ih + (size_t)row * H);
    float acc = 0.f;
#pragma unroll
    for (int it = 0; it < 4; ++it)
        acc += dot4(w4[lane + it * 64], sx4[lane + it * 64]);
    acc = wave_reduce(acc);
    if (lane == 0) gi_s[wid] = acc + b_ih[row];
    __syncthreads();
    if (tid < 4) {
        const int t = blockIdx.x * 4 + tid;
        const float ir = gi_s[tid], iz = gi_s[4 + tid], in_ = gi_s[8 + tid];
        const float hr = ws[OFF_GH + t];
        const float hz = ws[OFF_GH + H + t];
        const float hn = ws[OFF_GH + 2 * H + t];
        const float r = 1.f / (1.f + expf(-(ir + hr)));
        const float z = 1.f / (1.f + expf(-(iz + hz)));
        const float n = tanhf(in_ + r * hn);
        out[V + t] = (1.f - z) * n + z * hid[t];
    }
}

// ---- D: big out-proj GEMV (wave/row, 16 rows/block) + (m,s) partials ------
__global__ __launch_bounds__(1024) void kD(const float* __restrict__ out_W,
                                           const float* __restrict__ out_b,
                                           const float* __restrict__ hnew,
                                           float* __restrict__ ws) {
    __shared__ float4 sh[256];  // h_new
    __shared__ float srow[16];
    const int tid = threadIdx.x;
    if (tid < 256) sh[tid] = reinterpret_cast<const float4*>(hnew)[tid];
    __syncthreads();
    const int lane = tid & 63, wid = tid >> 6;
    const int row = blockIdx.x * 16 + wid;
    float logit = -INFINITY;
    if (row < V) {
        const float4* w4 = reinterpret_cast<const float4*>(out_W + (size_t)row * H);
        float acc = 0.f;
#pragma unroll
        for (int it = 0; it < 4; ++it)
            acc += dot4(w4[lane + it * 64], sh[lane + it * 64]);
        acc = wave_reduce(acc);
        if (lane == 0) {
            logit = acc + out_b[row];
            ws[OFF_LOG + row] = logit;
        }
    }
    if (lane == 0) srow[wid] = logit;
    __syncthreads();
    if (tid == 0) {
        float m = -INFINITY;
        for (int i = 0; i < 16; ++i) m = fmaxf(m, srow[i]);
        float s = 0.f;
        for (int i = 0; i < 16; ++i)
            if (srow[i] > -INFINITY) s += expf(srow[i] - m);
        ws[OFF_PAIR + 2 * blockIdx.x] = m;
        ws[OFF_PAIR + 2 * blockIdx.x + 1] = s;
    }
}

// ---- E: redundant (m,s) combine per block + log-softmax write -------------
__global__ __launch_bounds__(256) void kE(const float* __restrict__ ws,
                                          float* __restrict__ out) {
    const int tid = threadIdx.x;
    float m = -INFINITY, s = 0.f;
    for (int i = tid; i < NBLKD; i += 256) {
        const float mi = ws[OFF_PAIR + 2 * i];
        const float si = ws[OFF_PAIR + 2 * i + 1];
        const float M = fmaxf(m, mi);
        s = s * expf(m - M) + si * expf(mi - M);
        m = M;
    }
    for (int off = 32; off > 0; off >>= 1) {
        const float mo = __shfl_down(m, off);
        const float so = __shfl_down(s, off);
        const float M = fmaxf(m, mo);
        s = s * expf(m - M) + so * expf(mo - M);
        m = M;
    }
    __shared__ float sm[4], ss[4];
    __shared__ float fin[2];
    const int lane = tid & 63, wid = tid >> 6;
    if (lane == 0) { sm[wid] = m; ss[wid] = s; }
    __syncthreads();
    if (tid == 0) {
        float M = sm[0], S = ss[0];
        for (int i = 1; i < 4; ++i) {
            const float Mn = fmaxf(M, sm[i]);
            S = S * expf(M - Mn) + ss[i] * expf(sm[i] - Mn);
            M = Mn;
        }
        fin[0] = M;
        fin[1] = logf(S);
    }
    __syncthreads();
    const int i = blockIdx.x * 256 + tid;
    if (i < V) out[i] = ws[OFF_LOG + i] - fin[0] - fin[1];
}

extern "C" void kernel_launch(void* const* d_in, const int* in_sizes, int n_in,
                              void* d_out, int out_size, void* d_ws, size_t ws_size,
                              hipStream_t stream) {
    const int*   idx    = (const int*)d_in[0];
    const float* hid    = (const float*)d_in[1];
    const float* enc    = (const float*)d_in[2];
    const float* emb    = (const float*)d_in[3];
    const float* attn_W = (const float*)d_in[4];
    const float* attn_b = (const float*)d_in[5];
    const float* comb_W = (const float*)d_in[6];
    const float* comb_b = (const float*)d_in[7];
    const float* w_ih   = (const float*)d_in[8];
    const float* w_hh   = (const float*)d_in[9];
    const float* b_ih   = (const float*)d_in[10];
    const float* b_hh   = (const float*)d_in[11];
    const float* out_W  = (const float*)d_in[12];
    const float* out_b  = (const float*)d_in[13];
    float* out = (float*)d_out;
    float* ws  = (float*)d_ws;

    kA<<<64 + 768, 256, 0, stream>>>(idx, hid, emb, attn_W, attn_b, w_hh, b_hh, ws);
    kB<<<256, 256, 0, stream>>>(idx, emb, enc, comb_W, comb_b, ws, out);
    kC<<<256, 768, 0, stream>>>(w_ih, b_ih, hid, ws, out);
    kD<<<NBLKD, 1024, 0, stream>>>(out_W, out_b, out + V, ws);
    kE<<<(V + 255) / 256, 256, 0, stream>>>(ws, out);
}